// Round 4
// baseline (257.470 us; speedup 1.0000x reference)
//
#include <hip/hip_runtime.h>

// Fused: h = relu(X @ M + d), s0 = sum(h), where
//   M = W^T @ RW  (20x20, precomputed once per call),
//   d = b @ RW + 1 (20,)
// algebraically identical to relu((X@W^T + b)@RW + 1).
// Then n = #halvings of f32(s0) until <= 1; out = f32(s0) * 2^-n.
//
// Round-4 key change: round-2's LDS-broadcast RPT=4 structure, but with
// __launch_bounds__(256, 2). Round 2's VGPR_Count=60 revealed the compiler
// targeting 8 waves/SIMD (64-VGPR budget) and spilling the ~110-float
// working set to scratch (-> 92 us L2/scratch-bound). min-waves=2 lifts the
// cap to 256 VGPRs; working set stays in registers at 4 waves/SIMD.

#define D 20
#define BLOCK 256
#define RPT 4  // rows per thread; nrows % 4 == 0 and row0 % 4 == 0 -> no partial tails

// d_ws layout: [0,8) double acc; byte 16: float Mt[400]; then float dvec[20].
// Mt[j*D + k] = M[k][j] = sum_i W[i][k] * RW[i][j]   (j-major)

__global__ void setup_kernel(const float* __restrict__ W,
                             const float* __restrict__ b,
                             const float* __restrict__ RW,
                             double* __restrict__ acc,
                             float* __restrict__ Mt,
                             float* __restrict__ dvec) {
    const int tid = threadIdx.x;
    if (tid == 0) acc[0] = 0.0;  // d_ws is poisoned 0xAA before every launch
    for (int idx = tid; idx < D * D; idx += blockDim.x) {
        const int j = idx / D, k = idx % D;
        float s = 0.0f;
        for (int i = 0; i < D; ++i)
            s = fmaf(W[i * D + k], RW[i * D + j], s);
        Mt[idx] = s;  // idx == j*D + k
    }
    if (tid < D) {
        float s = 1.0f;
        for (int i = 0; i < D; ++i)
            s = fmaf(b[i], RW[i * D + tid], s);
        dvec[tid] = s;
    }
}

__global__ void __launch_bounds__(BLOCK, 2)
fused_mlp_sum(const float* __restrict__ X,
              const float* __restrict__ Mt,
              const float* __restrict__ dvec,
              double* __restrict__ acc,
              int nrows) {
    // sM4[j*5 + q] = float4 of M[4q..4q+3][j]; 16B-aligned -> ds_read_b128
    __shared__ float4 sM4[D * 5];
    __shared__ float sd[D];
    __shared__ float wave_sums[BLOCK / 64];

    const int tid = threadIdx.x;
    {
        const float4* Mt4 = (const float4*)Mt;  // Mt is 16B-aligned (ws+16)
        for (int i = tid; i < D * 5; i += BLOCK) sM4[i] = Mt4[i];
        if (tid < D) sd[tid] = dvec[tid];
    }
    __syncthreads();

    const long long t = (long long)blockIdx.x * BLOCK + tid;
    const long long row0 = t * RPT;
    float lsum = 0.0f;

    if (row0 < nrows) {  // row0 % 4 == 0 and nrows % 4 == 0 -> all 4 rows valid
        const float* xp = X + row0 * D;

        float x[RPT][D];
#pragma unroll
        for (int r = 0; r < RPT; ++r) {
#pragma unroll
            for (int q = 0; q < 5; ++q) {
                float4 v = ((const float4*)(xp + r * D))[q];
                x[r][4 * q + 0] = v.x; x[r][4 * q + 1] = v.y;
                x[r][4 * q + 2] = v.z; x[r][4 * q + 3] = v.w;
            }
        }

#pragma unroll
        for (int j = 0; j < D; ++j) {
            float tr[RPT];
            const float dj = sd[j];
#pragma unroll
            for (int r = 0; r < RPT; ++r) tr[r] = dj;
#pragma unroll
            for (int q = 0; q < 5; ++q) {
                const float4 mv = sM4[j * 5 + q];  // broadcast ds_read_b128
#pragma unroll
                for (int r = 0; r < RPT; ++r) {
                    tr[r] = fmaf(x[r][4 * q + 0], mv.x, tr[r]);
                    tr[r] = fmaf(x[r][4 * q + 1], mv.y, tr[r]);
                    tr[r] = fmaf(x[r][4 * q + 2], mv.z, tr[r]);
                    tr[r] = fmaf(x[r][4 * q + 3], mv.w, tr[r]);
                }
            }
#pragma unroll
            for (int r = 0; r < RPT; ++r) lsum += fmaxf(tr[r], 0.0f);
        }
    }

    // Wave (64-lane) shuffle reduction -> block LDS -> one double atomic.
#pragma unroll
    for (int off = 32; off > 0; off >>= 1)
        lsum += __shfl_down(lsum, off, 64);
    if ((tid & 63) == 0) wave_sums[tid >> 6] = lsum;
    __syncthreads();
    if (tid == 0) {
        float bs = 0.0f;
#pragma unroll
        for (int w = 0; w < BLOCK / 64; ++w) bs += wave_sums[w];
        atomicAdd(acc, (double)bs);
    }
}

__global__ void finalize_kernel(const double* __restrict__ acc,
                                float* __restrict__ out) {
    double s0 = acc[0];
    float s = (float)s0;   // reference's s0 is f32
    int n = 0;
    while (s > 1.0f) { ++n; s *= 0.5f; }  // exact power-of-2 halvings
    out[0] = s;            // == f32(s0) * 2^-n
}

extern "C" void kernel_launch(void* const* d_in, const int* in_sizes, int n_in,
                              void* d_out, int out_size, void* d_ws, size_t ws_size,
                              hipStream_t stream) {
    const float* X  = (const float*)d_in[0];
    const float* W  = (const float*)d_in[1];
    const float* b  = (const float*)d_in[2];
    const float* RW = (const float*)d_in[3];
    float* out = (float*)d_out;

    double* acc = (double*)d_ws;
    float*  Mt  = (float*)((char*)d_ws + 16);
    float*  dv  = Mt + D * D;

    const int nrows = in_sizes[0] / D;  // 2,000,000

    setup_kernel<<<1, 256, 0, stream>>>(W, b, RW, acc, Mt, dv);

    const long long nthreads = ((long long)nrows + RPT - 1) / RPT;  // 500,000
    const int blocks = (int)((nthreads + BLOCK - 1) / BLOCK);       // 1954
    fused_mlp_sum<<<blocks, BLOCK, 0, stream>>>(X, Mt, dv, acc, nrows);
    finalize_kernel<<<1, 1, 0, stream>>>(acc, out);
}

// Round 5
// 231.118 us; speedup vs baseline: 1.1140x; 1.1140x over previous
//
#include <hip/hip_runtime.h>

// Fused: h = relu(X @ M + d), s0 = sum(h), where
//   M = W^T @ RW (20x20), d = b @ RW + 1 (20,)  -- precomputed by setup_kernel.
// Algebraically identical to relu((X@W^T + b)@RW + 1). Then n = #halvings of
// f32(s0) until <= 1; out = f32(s0) * 2^-n (exact power-of-2 scaling).
//
// Round-5 key change: UNIFORM control flow in the main kernel. The AMDGPU
// backend only scalarizes uniform-address global loads (s_load -> SGPR,
// scalar pipe) when they sit in uniform CF with provable noclobber. Rounds
// 1-4 all delivered M through a saturated path (per-lane VMEM under a
// divergent `if` in R3; DS broadcast in R1/R4; scratch spill in R2). Here:
// no branch -- tail lanes clamp their row base with a v_cndmask select and
// mask their sum at the end. M/d loads become s_load from sK$ (1.6 KB),
// concurrent with VALU; lanes hold only x0,x1 (40 VGPRs) -> no spill.
// Also: per-block plain-store partials (no contended same-address atomic);
// finalize kernel reduces them.

#define D 20
#define BLOCK 256
#define RPT 2  // rows per thread

// d_ws layout:
//   [0, 32768)                : double partials[4096] (one per block)
//   [32768, 32768+1600)       : float Mt[400], Mt[j*D+k] = M[k][j]
//   [+1600, +1680)            : float dvec[20]
#define WS_PARTIALS_BYTES 32768

__global__ void setup_kernel(const float* __restrict__ W,
                             const float* __restrict__ b,
                             const float* __restrict__ RW,
                             float* __restrict__ Mt,
                             float* __restrict__ dvec) {
    const int tid = threadIdx.x;
    for (int idx = tid; idx < D * D; idx += blockDim.x) {
        const int j = idx / D, k = idx % D;
        float s = 0.0f;
        for (int i = 0; i < D; ++i)
            s = fmaf(W[i * D + k], RW[i * D + j], s);
        Mt[idx] = s;  // idx == j*D + k
    }
    if (tid < D) {
        float s = 1.0f;
        for (int i = 0; i < D; ++i)
            s = fmaf(b[i], RW[i * D + tid], s);
        dvec[tid] = s;
    }
}

__global__ void __launch_bounds__(BLOCK)
fused_mlp_sum(const float* __restrict__ X,
              const float* __restrict__ Mt,
              const float* __restrict__ dvec,
              double* __restrict__ partials,
              int nrows) {
    __shared__ float wave_sums[BLOCK / 64];

    const int tid = threadIdx.x;
    const long long t = (long long)blockIdx.x * BLOCK + tid;
    const long long row0 = t * RPT;
    const bool valid = row0 < (long long)nrows;
    // Clamp instead of branch: control flow stays UNIFORM so the backend can
    // scalarize the Mt/dvec loads (s_load). Clamped lanes read real memory
    // (in-bounds) and are masked out of the sum below.
    const long long rbase = valid ? row0 : (long long)nrows - RPT;
    const float* xp = X + rbase * D;

    float x0[D], x1[D];
#pragma unroll
    for (int q = 0; q < 5; ++q) {
        float4 v = ((const float4*)xp)[q];
        x0[4 * q + 0] = v.x; x0[4 * q + 1] = v.y;
        x0[4 * q + 2] = v.z; x0[4 * q + 3] = v.w;
        float4 u = ((const float4*)(xp + D))[q];
        x1[4 * q + 0] = u.x; x1[4 * q + 1] = u.y;
        x1[4 * q + 2] = u.z; x1[4 * q + 3] = u.w;
    }

    float lsum = 0.0f;
#pragma unroll
    for (int j = 0; j < D; ++j) {
        float t0 = dvec[j];   // uniform addr + uniform CF -> s_load (SGPR)
        float t1 = t0;
#pragma unroll
        for (int k = 0; k < D; ++k) {
            const float m = Mt[j * D + k];  // uniform -> s_load, scalar pipe
            t0 = fmaf(x0[k], m, t0);        // v_fma with SGPR src
            t1 = fmaf(x1[k], m, t1);
        }
        lsum += fmaxf(t0, 0.0f) + fmaxf(t1, 0.0f);
    }
    lsum = valid ? lsum : 0.0f;  // mask clamped tail lanes

    // Wave (64-lane) shuffle reduction -> block LDS -> one plain store.
#pragma unroll
    for (int off = 32; off > 0; off >>= 1)
        lsum += __shfl_down(lsum, off, 64);
    if ((tid & 63) == 0) wave_sums[tid >> 6] = lsum;
    __syncthreads();
    if (tid == 0) {
        float bs = 0.0f;
#pragma unroll
        for (int w = 0; w < BLOCK / 64; ++w) bs += wave_sums[w];
        partials[blockIdx.x] = (double)bs;  // no atomic: one slot per block
    }
}

__global__ void __launch_bounds__(1024)
finalize_kernel(const double* __restrict__ partials, int nparts,
                float* __restrict__ out) {
    __shared__ double wsum[16];
    const int tid = threadIdx.x;
    double s = 0.0;
    for (int i = tid; i < nparts; i += 1024) s += partials[i];
#pragma unroll
    for (int off = 32; off > 0; off >>= 1)
        s += __shfl_down(s, off, 64);
    if ((tid & 63) == 0) wsum[tid >> 6] = s;
    __syncthreads();
    if (tid == 0) {
        double s0 = 0.0;
#pragma unroll
        for (int w = 0; w < 16; ++w) s0 += wsum[w];
        float f = (float)s0;   // reference's s0 is f32
        int n = 0;
        while (f > 1.0f) { ++n; f *= 0.5f; }  // exact power-of-2 halvings
        out[0] = f;
    }
}

extern "C" void kernel_launch(void* const* d_in, const int* in_sizes, int n_in,
                              void* d_out, int out_size, void* d_ws, size_t ws_size,
                              hipStream_t stream) {
    const float* X  = (const float*)d_in[0];
    const float* W  = (const float*)d_in[1];
    const float* b  = (const float*)d_in[2];
    const float* RW = (const float*)d_in[3];
    float* out = (float*)d_out;

    double* partials = (double*)d_ws;
    float*  Mt = (float*)((char*)d_ws + WS_PARTIALS_BYTES);
    float*  dv = Mt + D * D;

    const int nrows = in_sizes[0] / D;  // 2,000,000

    setup_kernel<<<1, 256, 0, stream>>>(W, b, RW, Mt, dv);

    const long long nthreads = ((long long)nrows + RPT - 1) / RPT;  // 1,000,000
    const int blocks = (int)((nthreads + BLOCK - 1) / BLOCK);       // 3907
    fused_mlp_sum<<<blocks, BLOCK, 0, stream>>>(X, Mt, dv, partials, nrows);
    finalize_kernel<<<1, 1024, 0, stream>>>(partials, blocks, out);
}